// Round 2
// baseline (194.055 us; speedup 1.0000x reference)
//
#include <hip/hip_runtime.h>

// SimpleEdgeModel, round 2: producer/consumer wave-specialized edge kernel.
//
// out[b,i,j] = Wo·relu(W3ᵀ·relu(W2ᵀ·relu(g[b,j]-g[b,i]+bc1)+bc2)+bc3)+bo,
// g = nodeMLP(x)@Wc1 (layer c1 is linear -> folded per node).
//
// Edge kernel: 512 persistent blocks = (b, 64-j-range, 16-i-range), 4 waves.
//   waves 0-1 (producers): layer2 as e2ᵀ = W2ᵀ·e1ᵀ (W2ᵀ A-frags in 128 VGPRs,
//     e1 B-frags built in registers from f16 g_j cache), write e2 to LDS slots.
//   waves 2-3 (consumers): read layer-3 A-frags straight from those slots
//     (the C->A transpose is absorbed by slot addressing), W3 B-frags in
//     128 VGPRs, epilogue dot with Wo + shfl reduce + store.
//   1 block barrier per unit, double-buffered handoff (34816 B LDS).

typedef _Float16 half_t;
typedef __attribute__((ext_vector_type(8))) _Float16 f16x8;
typedef __attribute__((ext_vector_type(4))) _Float16 f16x4;
typedef __attribute__((ext_vector_type(4))) float f32x4;

#define JBLK 64
#define UBLK 16
#define SSTRIDE 272                 // 16 slots x 16B + 16B pad (68 dwords, bank-spread)
#define JTSTRIDE (16 * SSTRIDE)     // 4352 B per 16-row j-tile
#define BUFSTRIDE (4 * JTSTRIDE)    // 17408 B per pipeline buffer

// ---------------------------------------------------------------------------
// prep_kernel: blocks 0..255 = node MLP (4 nodes/block, 2/thread);
//              blocks 256..271 = pack Wc2/Wc3 into MFMA fragment order.
// Fragment pack (nt,ks): elem L*8+j = W[ks*32+(L>>4)*8+j][nt*16+(L&15)] —
// this single order serves BOTH W2ᵀ-as-A-frag and W3-as-B-frag (mirror layouts).
// ---------------------------------------------------------------------------
__global__ __launch_bounds__(256) void prep_kernel(
    const float* __restrict__ x, const float* __restrict__ Wa, const float* __restrict__ ba,
    const float* __restrict__ Wb, const float* __restrict__ bb, const float* __restrict__ Wc1,
    const float* __restrict__ Wc2, const float* __restrict__ Wc3,
    float* __restrict__ g, half_t* __restrict__ W2f, half_t* __restrict__ W3f)
{
  const int t = threadIdx.x;
  if (blockIdx.x >= 256) {
    const int bid = blockIdx.x - 256;          // 0..15: layer(1b) x ntile(3b)
    const int layer = bid >> 3, nt = bid & 7;
    const int ks = t >> 6, L = t & 63;
    const float* src = layer ? Wc3 : Wc2;
    half_t* dst = layer ? W3f : W2f;
    #pragma unroll
    for (int j = 0; j < 8; j++) {
      const int k = ks * 32 + (L >> 4) * 8 + j;
      const int n = nt * 16 + (L & 15);
      dst[(nt * 4 + ks) * 512 + L * 8 + j] = (half_t)src[k * 128 + n];
    }
    return;
  }
  // ---- node MLP: nodes n0..n0+3; thread handles (col, 2 nodes) ----
  __shared__ float sx[64 * 6];     // [c][node(4)+pad2] stride 6
  __shared__ float sh1[128 * 6];
  __shared__ float sh2[128 * 6];
  const int n0 = blockIdx.x * 4;
  const int col = t & 127, half = t >> 7;      // nodes half*2, half*2+1

  sx[(t & 63) * 6 + (t >> 6)] = x[(n0 + (t >> 6)) * 64 + (t & 63)];
  __syncthreads();

  float a0 = ba[col], a1 = a0;
  #pragma unroll
  for (int cc = 0; cc < 64; cc++) {
    const float wv = Wa[cc * 128 + col];
    const float2 xv = *(const float2*)(sx + cc * 6 + half * 2);
    a0 = fmaf(xv.x, wv, a0); a1 = fmaf(xv.y, wv, a1);
  }
  *(float2*)(sh1 + col * 6 + half * 2) = make_float2(fmaxf(a0, 0.f), fmaxf(a1, 0.f));
  __syncthreads();

  float b0 = bb[col], b1 = b0;
  #pragma unroll
  for (int k = 0; k < 128; k++) {
    const float wv = Wb[k * 128 + col];
    const float2 hv = *(const float2*)(sh1 + k * 6 + half * 2);
    b0 = fmaf(hv.x, wv, b0); b1 = fmaf(hv.y, wv, b1);
  }
  *(float2*)(sh2 + col * 6 + half * 2) = make_float2(fmaxf(b0, 0.f), fmaxf(b1, 0.f));
  __syncthreads();

  float c0 = 0.f, c1 = 0.f;
  #pragma unroll
  for (int k = 0; k < 128; k++) {
    const float wv = Wc1[k * 128 + col];
    const float2 hv = *(const float2*)(sh2 + k * 6 + half * 2);
    c0 = fmaf(hv.x, wv, c0); c1 = fmaf(hv.y, wv, c1);
  }
  g[(n0 + half * 2 + 0) * 128 + col] = c0;     // raw g: bc1 added by producer
  g[(n0 + half * 2 + 1) * 128 + col] = c1;
}

// ---------------------------------------------------------------------------
// edge_kernel.
// Handoff slot math: producer lane (c,q), reg nt holds e2[j=jt*16+c][n2=nt*16+q*4+r],
// packed as 2 dwords (d: n2 = nt*16+4q+2d+{0,1}) -> b64 at slot S=2nt+(q>>1),
// byte (q&1)*8.  Consumer lane (c,q') frag ks' reads b128 at S=4ks'+2(q'>>1)+(q'&1):
// exactly A[m=c][k=ks'*32+8q'+jj] for layer 3.
// ---------------------------------------------------------------------------
__global__ __launch_bounds__(256, 2) void edge_kernel(
    const float* __restrict__ g, const half_t* __restrict__ W2f, const half_t* __restrict__ W3f,
    const float* __restrict__ bc1, const float* __restrict__ bc2, const float* __restrict__ bc3,
    const float* __restrict__ Wo, const float* __restrict__ bo, float* __restrict__ out)
{
  __shared__ uint4 hbuf[2 * BUFSTRIDE / 16];   // 34816 B, 16B-aligned
  char* hb = (char*)hbuf;

  const int t = threadIdx.x;
  const int lane = t & 63, w = t >> 6;
  const int c = lane & 15, q = lane >> 4;
  const bool is_prod = (w < 2);
  const int wv = is_prod ? w : (w - 2);        // role-local wave: jt tiles {2wv, 2wv+1}

  const int bid = blockIdx.x;                  // 512 = b(1) x jr(3) x ir(5)
  const int b  = bid >> 8;
  const int jr = (bid >> 5) & 7;
  const int ir = bid & 31;
  const int j0 = jr * JBLK, i0 = ir * UBLK;
  const float* gB = g + (size_t)b * 512 * 128;

  // ---- register-resident weight fragments (128 VGPRs): W2ᵀ-A for producers,
  //      W3-B for consumers; identical packed layout ----
  const half_t* Wsrc = is_prod ? W2f : W3f;
  f16x8 Wf[8][4];
  #pragma unroll
  for (int nt = 0; nt < 8; nt++)
    #pragma unroll
    for (int ks = 0; ks < 4; ks++)
      Wf[nt][ks] = *(const f16x8*)(Wsrc + (nt * 4 + ks) * 512 + lane * 8);

  // ---- producer: f16 cache of g_j + bc1 (32 VGPRs); lane c owns j = jt*16+c ----
  f16x8 gjc[2][4];
  // ---- consumer: epilogue constants ----
  float bc3v[8], wov[8], bo0 = 0.f;
  if (is_prod) {
    #pragma unroll
    for (int jtl = 0; jtl < 2; jtl++) {
      const int j = j0 + (wv * 2 + jtl) * 16 + c;
      const float* gj = gB + (size_t)j * 128;
      #pragma unroll
      for (int ks = 0; ks < 4; ks++) {
        const int k0 = ks * 32 + q * 8;
        const float4 v0 = *(const float4*)(gj + k0);
        const float4 v1 = *(const float4*)(gj + k0 + 4);
        const float4 b0 = *(const float4*)(bc1 + k0);
        const float4 b1 = *(const float4*)(bc1 + k0 + 4);
        f16x8 r;
        r[0] = (half_t)(v0.x + b0.x); r[1] = (half_t)(v0.y + b0.y);
        r[2] = (half_t)(v0.z + b0.z); r[3] = (half_t)(v0.w + b0.w);
        r[4] = (half_t)(v1.x + b1.x); r[5] = (half_t)(v1.y + b1.y);
        r[6] = (half_t)(v1.z + b1.z); r[7] = (half_t)(v1.w + b1.w);
        gjc[jtl][ks] = r;
      }
    }
  } else {
    #pragma unroll
    for (int nt = 0; nt < 8; nt++) {
      bc3v[nt] = bc3[nt * 16 + c];
      wov[nt]  = Wo[nt * 16 + c];
    }
    bo0 = bo[0];
  }

  // ---- pipelined unit loop: unit u = row i0+u; prod fills buf[u&1],
  //      cons drains buf[(u-1)&1]; one barrier per iteration ----
  for (int u = 0; u <= UBLK; u++) {
    if (is_prod) {
      if (u < UBLK) {
        const int i = i0 + u;
        float4 gi[4][2];
        #pragma unroll
        for (int ks = 0; ks < 4; ks++) {
          const int k0 = ks * 32 + q * 8;
          gi[ks][0] = *(const float4*)(gB + (size_t)i * 128 + k0);
          gi[ks][1] = *(const float4*)(gB + (size_t)i * 128 + k0 + 4);
        }
        #pragma unroll
        for (int jtl = 0; jtl < 2; jtl++) {
          const int jtg = wv * 2 + jtl;
          f32x4 acc[8];
          #pragma unroll
          for (int nt = 0; nt < 8; nt++) {           // fold bc2 into acc init
            const float4 bv = *(const float4*)(bc2 + nt * 16 + q * 4);
            acc[nt][0] = bv.x; acc[nt][1] = bv.y; acc[nt][2] = bv.z; acc[nt][3] = bv.w;
          }
          #pragma unroll
          for (int ks = 0; ks < 4; ks++) {
            const f16x8 gj = gjc[jtl][ks];
            const float* gip = (const float*)&gi[ks][0];
            f16x8 e1;
            #pragma unroll
            for (int e = 0; e < 8; e++)
              e1[e] = (half_t)fmaxf((float)gj[e] - gip[e], 0.f);
            #pragma unroll
            for (int nt = 0; nt < 8; nt++)
              acc[nt] = __builtin_amdgcn_mfma_f32_16x16x32_f16(Wf[nt][ks], e1, acc[nt], 0, 0, 0);
          }
          char* base = hb + (u & 1) * BUFSTRIDE + jtg * JTSTRIDE;
          #pragma unroll
          for (int nt = 0; nt < 8; nt++) {
            const int S = nt * 2 + (q >> 1);
            f16x4 e2v;
            e2v[0] = (half_t)fmaxf(acc[nt][0], 0.f);
            e2v[1] = (half_t)fmaxf(acc[nt][1], 0.f);
            e2v[2] = (half_t)fmaxf(acc[nt][2], 0.f);
            e2v[3] = (half_t)fmaxf(acc[nt][3], 0.f);
            *(f16x4*)(base + S * SSTRIDE + c * 16 + (q & 1) * 8) = e2v;
          }
        }
      }
    } else {
      if (u >= 1) {
        const int i = i0 + u - 1;
        const char* bufr = hb + ((u - 1) & 1) * BUFSTRIDE;
        #pragma unroll
        for (int jtl = 0; jtl < 2; jtl++) {
          const int jtg = wv * 2 + jtl;
          const char* base = bufr + jtg * JTSTRIDE;
          f16x8 af[4];
          #pragma unroll
          for (int ks = 0; ks < 4; ks++) {
            const int S = ks * 4 + (q >> 1) * 2 + (q & 1);
            af[ks] = *(const f16x8*)(base + S * SSTRIDE + c * 16);
          }
          f32x4 acc[8];
          #pragma unroll
          for (int nt = 0; nt < 8; nt++) { acc[nt][0] = 0.f; acc[nt][1] = 0.f; acc[nt][2] = 0.f; acc[nt][3] = 0.f; }
          #pragma unroll
          for (int ks = 0; ks < 4; ks++)
            #pragma unroll
            for (int nt = 0; nt < 8; nt++)
              acc[nt] = __builtin_amdgcn_mfma_f32_16x16x32_f16(af[ks], Wf[nt][ks], acc[nt], 0, 0, 0);
          // epilogue: out[j] = sum_n3 relu(e3+bc3)*Wo + bo; n3 spread over c-lanes x nt
          float p[4] = {0.f, 0.f, 0.f, 0.f};
          #pragma unroll
          for (int nt = 0; nt < 8; nt++)
            #pragma unroll
            for (int r = 0; r < 4; r++)
              p[r] += fmaxf(acc[nt][r] + bc3v[nt], 0.f) * wov[nt];
          #pragma unroll
          for (int mask = 1; mask <= 8; mask <<= 1)
            #pragma unroll
            for (int r = 0; r < 4; r++)
              p[r] += __shfl_xor(p[r], mask, 64);
          if (c == 0) {
            float4 o = make_float4(p[0] + bo0, p[1] + bo0, p[2] + bo0, p[3] + bo0);
            *(float4*)(out + ((size_t)(b * 512 + i)) * 512 + j0 + jtg * 16 + q * 4) = o;
          }
        }
      }
    }
    __syncthreads();
  }
}

// ---------------------------------------------------------------------------
extern "C" void kernel_launch(void* const* d_in, const int* in_sizes, int n_in,
                              void* d_out, int out_size, void* d_ws, size_t ws_size,
                              hipStream_t stream)
{
  const float* x   = (const float*)d_in[0];
  const float* Wa  = (const float*)d_in[1];
  const float* ba  = (const float*)d_in[2];
  const float* Wb  = (const float*)d_in[3];
  const float* bb  = (const float*)d_in[4];
  const float* Wc1 = (const float*)d_in[5];
  const float* bc1 = (const float*)d_in[6];
  const float* Wc2 = (const float*)d_in[7];
  const float* bc2 = (const float*)d_in[8];
  const float* Wc3 = (const float*)d_in[9];
  const float* bc3 = (const float*)d_in[10];
  const float* Wo  = (const float*)d_in[11];
  const float* bo  = (const float*)d_in[12];
  float* out = (float*)d_out;

  // workspace: g (1024x128 f32, 512KB) | W2f (32KB f16) | W3f (32KB f16)
  char* ws = (char*)d_ws;
  float*  gbuf = (float*)ws;
  half_t* W2f  = (half_t*)(ws + 524288);
  half_t* W3f  = (half_t*)(ws + 524288 + 32768);

  prep_kernel<<<272, 256, 0, stream>>>(x, Wa, ba, Wb, bb, Wc1, Wc2, Wc3, gbuf, W2f, W3f);
  edge_kernel<<<512, 256, 0, stream>>>(gbuf, W2f, W3f, bc1, bc2, bc3, Wo, bo, out);
}